// Round 5
// baseline (358.146 us; speedup 1.0000x reference)
//
#include <hip/hip_runtime.h>
#include <math.h>

typedef _Float16 f16_t;
typedef _Float16 f16x8 __attribute__((ext_vector_type(8)));
typedef _Float16 f16x4 __attribute__((ext_vector_type(4)));
typedef _Float16 f16x2 __attribute__((ext_vector_type(2)));
typedef __fp16 h16x2 __attribute__((ext_vector_type(2)));
typedef float f32x4 __attribute__((ext_vector_type(4)));

#define LDS_BYTES 37376

// fp32 -> fp16 weights into d_ws, FRAGMENT-LINEAR: for global chunk ck (0..11:
// W1 ck0..3, W2 ck0..7) and feat-16-group f (0..15), the 1 KB block at
// (ck*16+f)*1024 bytes holds the MFMA A-fragment in exact lane order:
// lane l = q*16+c, byte [l*16 .. l*16+16) = feats f*16+c, k = q*8..q*8+7.
// Waves load weights STRAIGHT to VGPRs (1 KB coalesced per load) -- no LDS.
__global__ void wconv(const float* __restrict__ W1, const float* __restrict__ W2,
                      f16_t* __restrict__ o) {
  int i = blockIdx.x * 256 + threadIdx.x;  // 0..65535
  if (i < 32768) {
    int n = i >> 7, k = i & 127;
    int ck = k >> 5, q = (k >> 3) & 3, j = k & 7;
    int f = n >> 4, c = n & 15;
    o[ck * 8192 + f * 512 + (q * 16 + c) * 8 + j] = (f16_t)W1[i];
  }
  {
    int n = i >> 8, k = i & 255;
    int ck = k >> 5, q = (k >> 3) & 3, j = k & 7;
    int f = n >> 4, c = n & 15;
    o[32768 + ck * 8192 + f * 512 + (q * 16 + c) * 8 + j] = (f16_t)W2[i];
  }
}

__device__ __forceinline__ f16x2 pk2(float a, float b) {
  union { h16x2 h; f16x2 f; } u;
  u.h = __builtin_amdgcn_cvt_pkrtz(a, b);
  return u.f;
}

#define COMP(v, r) ((r) == 0 ? (v).x : (r) == 1 ? (v).y : (r) == 2 ? (v).z : (v).w)

// lgkm-only barrier: orders LDS data without draining VMEM -- weight loads in
// VGPR double-buffers stay in flight across every barrier (they are consumed
// by same-thread data deps only; no cross-thread visibility needed).
#define LGKMBAR() do { \
    asm volatile("s_waitcnt lgkmcnt(0)" ::: "memory"); \
    __builtin_amdgcn_s_barrier(); } while (0)

// Transposed fused MLP: D[feat][edge] = W @ x^T. Tile = 64 edges, 1024 threads,
// 16 waves as 8 feat-rows (32 feats) x 2 edge-cols (32 edges). acc[2][2].
// ROUND-5 CHANGE: weights NEVER touch LDS. r0-r4 showed a ~253us floor
// invariant to occupancy (44%->86%), staging drain (counted vmcnt), and
// staging volume -- the saturated resource is the LDS pipe (~1MB/tile:
// 192KB stage-in + 384KB af reads + 384KB bf reads). Weights are 192KB,
// L2-resident, read-only = Common-mistake #7. Now each wave buffer-loads its
// private af fragments straight to VGPRs (1KB coalesced, fragment-linear
// layout from wconv), register-double-buffered 2 chunks deep. LDS traffic
// -53%; the two GEMM k-loops contain ZERO barriers; 7 lgkm-only barriers
// total (was 17 with vmcnt drains). LDS 37376 B -> 2 blocks x 16 waves/CU.
__global__ __launch_bounds__(1024) void fused_mlp(
    const float* __restrict__ h,
    const int* __restrict__ src,
    const int* __restrict__ dst,
    const f16_t* __restrict__ wks,
    const float* __restrict__ b1, const float* __restrict__ g1, const float* __restrict__ be1,
    const float* __restrict__ b2, const float* __restrict__ g2, const float* __restrict__ be2,
    const float* __restrict__ w3, const float* __restrict__ b3,
    float* __restrict__ out, int E, int nrows) {
  extern __shared__ __attribute__((aligned(16))) char smem[];
  f16_t* xbuf = (f16_t*)smem;               // x0 [64][128]; later x1 [64][256] (32 KB)
  float* ssum = (float*)(smem + 32768);     // [8 wf][64 e] (LN1, LN2, then p partials)
  float* ssq  = (float*)(smem + 34816);     // [8 wf][64 e]
  float* smean = (float*)(smem + 36864);    // [64]
  float* srstd = (float*)(smem + 37120);    // [64]

  const int t = threadIdx.x;
  const int ebase = blockIdx.x * 64;

  const int lane = t & 63;
  const int wave = t >> 6;   // 0..15
  const int wf = wave >> 1;  // 0..7: 32 feats each
  const int we = wave & 1;   // 0..1: 32 edges each
  const int c = lane & 15;
  const int q = lane >> 4;
  const int featBase = wf * 32;
  const int e0 = we * 32 + c, e1 = e0 + 16;

  // Per-wave weight fragment pointer: + msf*512 selects the 16-feat half,
  // + ck*8192 selects the k-chunk. Each load is 1 KB, perfectly coalesced.
  const f16_t* wp = wks + (wf * 2) * 512 + lane * 8;

  // Weight prologue: chunks 0,1 into the 2-deep register ring (in flight
  // through the gather; compiler inserts counted vmcnt waits at first use).
  f16x8 afb[2][2];
  afb[0][0] = *(const f16x8*)(wp);
  afb[0][1] = *(const f16x8*)(wp + 512);
  afb[1][0] = *(const f16x8*)(wp + 8192);
  afb[1][1] = *(const f16x8*)(wp + 8192 + 512);

  // ---------- gather: x0[m][k] = h[src][k]*h[dst][k], fp16, swizzled stride-128 ----
  // 16 threads per edge, 8 floats each -> one f16x8 group per thread.
  {
    const int m = t >> 4;   // edge 0..63
    const int j = t & 15;   // 8-float k-slice = k-group j
    const int e = ebase + m;
    f16_t* xrow = xbuf + m * 128;
    const int g0 = (j ^ (m & 15)) & 15;
    if (e < E) {
      int si = src[e], di = dst[e];
      si = ((unsigned)si < (unsigned)nrows) ? si : 0;
      di = ((unsigned)di < (unsigned)nrows) ? di : 0;
      const float* hs = h + (long long)si * 128 + j * 8;
      const float* hd = h + (long long)di * 128 + j * 8;
      const float4 a0 = *(const float4*)(hs);
      const float4 a1 = *(const float4*)(hs + 4);
      const float4 c0 = *(const float4*)(hd);
      const float4 c1 = *(const float4*)(hd + 4);
      union { f16x8 v8; f16x2 v2[4]; } u0;
      u0.v2[0] = pk2(a0.x * c0.x, a0.y * c0.y);
      u0.v2[1] = pk2(a0.z * c0.z, a0.w * c0.w);
      u0.v2[2] = pk2(a1.x * c1.x, a1.y * c1.y);
      u0.v2[3] = pk2(a1.z * c1.z, a1.w * c1.w);
      *(f16x8*)(xrow + g0 * 8) = u0.v8;
    } else {
      f16x8 z = {};
      *(f16x8*)(xrow + g0 * 8) = z;
    }
  }
  LGKMBAR();  // b1: x0 visible (weight loads still in flight)

  // ---------- GEMM1: K=128, chunks 0..3, ZERO barriers ----------
  f32x4 acc[2][2];
#pragma unroll
  for (int msf = 0; msf < 2; ++msf)
#pragma unroll
    for (int n = 0; n < 2; ++n) acc[msf][n] = (f32x4){0.f, 0.f, 0.f, 0.f};

#pragma unroll
  for (int j = 0; j < 4; ++j) {
    const int gp = ((j * 4 + q) ^ c) & 15;
    f16x8 b0 = *(const f16x8*)(xbuf + e0 * 128 + gp * 8);
    f16x8 b1v = *(const f16x8*)(xbuf + e1 * 128 + gp * 8);
    f16x8 a0 = afb[j & 1][0], a1 = afb[j & 1][1];
    if (j < 2) {  // prefetch chunk j+2 into the slot just freed
      afb[j & 1][0] = *(const f16x8*)(wp + (j + 2) * 8192);
      afb[j & 1][1] = *(const f16x8*)(wp + (j + 2) * 8192 + 512);
    }
    acc[0][0] = __builtin_amdgcn_mfma_f32_16x16x32_f16(a0, b0, acc[0][0], 0, 0, 0);
    acc[0][1] = __builtin_amdgcn_mfma_f32_16x16x32_f16(a0, b1v, acc[0][1], 0, 0, 0);
    acc[1][0] = __builtin_amdgcn_mfma_f32_16x16x32_f16(a1, b0, acc[1][0], 0, 0, 0);
    acc[1][1] = __builtin_amdgcn_mfma_f32_16x16x32_f16(a1, b1v, acc[1][1], 0, 0, 0);
  }

  // GEMM2 weight prologue: chunks 4,5 -- in flight across the whole LN1 phase.
  afb[0][0] = *(const f16x8*)(wp + 4 * 8192);
  afb[0][1] = *(const f16x8*)(wp + 4 * 8192 + 512);
  afb[1][0] = *(const f16x8*)(wp + 5 * 8192);
  afb[1][1] = *(const f16x8*)(wp + 5 * 8192 + 512);

  // ---------- LN1 stats ----------
  {
    float s0 = 0.f, s1 = 0.f, q0 = 0.f, q1 = 0.f;
#pragma unroll
    for (int msf = 0; msf < 2; ++msf) {
      const float4 bv = *(const float4*)(b1 + featBase + msf * 16 + q * 4);
#pragma unroll
      for (int r = 0; r < 4; ++r) {
        const float b = COMP(bv, r);
        float v0 = acc[msf][0][r] + b, v1 = acc[msf][1][r] + b;
        acc[msf][0][r] = v0; acc[msf][1][r] = v1;
        s0 += v0; q0 += v0 * v0;
        s1 += v1; q1 += v1 * v1;
      }
    }
    s0 += __shfl_xor(s0, 16, 64); s0 += __shfl_xor(s0, 32, 64);
    q0 += __shfl_xor(q0, 16, 64); q0 += __shfl_xor(q0, 32, 64);
    s1 += __shfl_xor(s1, 16, 64); s1 += __shfl_xor(s1, 32, 64);
    q1 += __shfl_xor(q1, 16, 64); q1 += __shfl_xor(q1, 32, 64);
    if (q == 0) {
      ssum[wf * 64 + e0] = s0; ssq[wf * 64 + e0] = q0;
      ssum[wf * 64 + e1] = s1; ssq[wf * 64 + e1] = q1;
    }
  }
  LGKMBAR();  // b2: partials visible

  if (t < 64) {
    float s = 0.f, sq = 0.f;
#pragma unroll
    for (int w = 0; w < 8; ++w) { s += ssum[w * 64 + t]; sq += ssq[w * 64 + t]; }
    float mu = s * (1.f / 256.f);
    float var = sq * (1.f / 256.f) - mu * mu;
    smean[t] = mu;
    srstd[t] = rsqrtf(var + 1e-5f);
  }
  LGKMBAR();  // b3: mean/rstd ready

  // ---------- LN1 normalize + ReLU -> x1 [64][256] (overwrites x0) ----------
  {
    const float rs0 = srstd[e0], nmr0 = -smean[e0] * rs0;
    const float rs1 = srstd[e1], nmr1 = -smean[e1] * rs1;
    const int j0 = (q & 1) * 4;
#pragma unroll
    for (int msf = 0; msf < 2; ++msf) {
      const float4 gv = *(const float4*)(g1 + featBase + msf * 16 + q * 4);
      const float4 bev = *(const float4*)(be1 + featBase + msf * 16 + q * 4);
      const int g = wf * 4 + msf * 2 + (q >> 1);  // feat 16B-group 0..31
      float v00, v01, v02, v03, v10, v11, v12, v13;
      v00 = fmaxf(fmaf(fmaf(acc[msf][0][0], rs0, nmr0), gv.x, bev.x), 0.f);
      v01 = fmaxf(fmaf(fmaf(acc[msf][0][1], rs0, nmr0), gv.y, bev.y), 0.f);
      v02 = fmaxf(fmaf(fmaf(acc[msf][0][2], rs0, nmr0), gv.z, bev.z), 0.f);
      v03 = fmaxf(fmaf(fmaf(acc[msf][0][3], rs0, nmr0), gv.w, bev.w), 0.f);
      v10 = fmaxf(fmaf(fmaf(acc[msf][1][0], rs1, nmr1), gv.x, bev.x), 0.f);
      v11 = fmaxf(fmaf(fmaf(acc[msf][1][1], rs1, nmr1), gv.y, bev.y), 0.f);
      v12 = fmaxf(fmaf(fmaf(acc[msf][1][2], rs1, nmr1), gv.z, bev.z), 0.f);
      v13 = fmaxf(fmaf(fmaf(acc[msf][1][3], rs1, nmr1), gv.w, bev.w), 0.f);
      union { f16x4 v4; f16x2 v2[2]; } h0, h1;
      h0.v2[0] = pk2(v00, v01); h0.v2[1] = pk2(v02, v03);
      h1.v2[0] = pk2(v10, v11); h1.v2[1] = pk2(v12, v13);
      const int gp0 = (g & 16) | ((g ^ e0) & 15);
      const int gp1 = (g & 16) | ((g ^ e1) & 15);
      *(f16x4*)(xbuf + e0 * 256 + gp0 * 8 + j0) = h0.v4;
      *(f16x4*)(xbuf + e1 * 256 + gp1 * 8 + j0) = h1.v4;
    }
  }
  LGKMBAR();  // b4: x1 visible

  // ---------- GEMM2: K=256, chunks 4..11, ZERO barriers ----------
  f32x4 acc2[2][2];
#pragma unroll
  for (int msf = 0; msf < 2; ++msf)
#pragma unroll
    for (int n = 0; n < 2; ++n) acc2[msf][n] = (f32x4){0.f, 0.f, 0.f, 0.f};

#pragma unroll
  for (int j = 0; j < 8; ++j) {   // global chunk 4+j
    const int g = j * 4 + q;  // 0..31
    const int gp0 = (g & 16) | ((g ^ e0) & 15);
    const int gp1 = (g & 16) | ((g ^ e1) & 15);
    f16x8 b0 = *(const f16x8*)(xbuf + e0 * 256 + gp0 * 8);
    f16x8 b1v = *(const f16x8*)(xbuf + e1 * 256 + gp1 * 8);
    f16x8 a0 = afb[j & 1][0], a1 = afb[j & 1][1];
    if (j < 6) {  // prefetch chunk 4+j+2
      afb[j & 1][0] = *(const f16x8*)(wp + (j + 6) * 8192);
      afb[j & 1][1] = *(const f16x8*)(wp + (j + 6) * 8192 + 512);
    }
    acc2[0][0] = __builtin_amdgcn_mfma_f32_16x16x32_f16(a0, b0, acc2[0][0], 0, 0, 0);
    acc2[0][1] = __builtin_amdgcn_mfma_f32_16x16x32_f16(a0, b1v, acc2[0][1], 0, 0, 0);
    acc2[1][0] = __builtin_amdgcn_mfma_f32_16x16x32_f16(a1, b0, acc2[1][0], 0, 0, 0);
    acc2[1][1] = __builtin_amdgcn_mfma_f32_16x16x32_f16(a1, b1v, acc2[1][1], 0, 0, 0);
  }

  // ---------- LN2 stats ----------
  {
    float s0 = 0.f, s1 = 0.f, q0 = 0.f, q1 = 0.f;
#pragma unroll
    for (int msf = 0; msf < 2; ++msf) {
      const float4 bv = *(const float4*)(b2 + featBase + msf * 16 + q * 4);
#pragma unroll
      for (int r = 0; r < 4; ++r) {
        const float b = COMP(bv, r);
        float v0 = acc2[msf][0][r] + b, v1 = acc2[msf][1][r] + b;
        acc2[msf][0][r] = v0; acc2[msf][1][r] = v1;
        s0 += v0; q0 += v0 * v0;
        s1 += v1; q1 += v1 * v1;
      }
    }
    s0 += __shfl_xor(s0, 16, 64); s0 += __shfl_xor(s0, 32, 64);
    q0 += __shfl_xor(q0, 16, 64); q0 += __shfl_xor(q0, 32, 64);
    s1 += __shfl_xor(s1, 16, 64); s1 += __shfl_xor(s1, 32, 64);
    q1 += __shfl_xor(q1, 16, 64); q1 += __shfl_xor(q1, 32, 64);
    if (q == 0) {
      ssum[wf * 64 + e0] = s0; ssq[wf * 64 + e0] = q0;
      ssum[wf * 64 + e1] = s1; ssq[wf * 64 + e1] = q1;
    }
  }
  LGKMBAR();  // b5

  if (t < 64) {
    float s = 0.f, sq = 0.f;
#pragma unroll
    for (int w = 0; w < 8; ++w) { s += ssum[w * 64 + t]; sq += ssq[w * 64 + t]; }
    float mu = s * (1.f / 256.f);
    float var = sq * (1.f / 256.f) - mu * mu;
    smean[t] = mu;
    srstd[t] = rsqrtf(var + 1e-5f);
  }
  LGKMBAR();  // b6

  // ---------- LN2 normalize + ReLU + dot(W3) + sigmoid ----------
  {
    const float rs0 = srstd[e0], nmr0 = -smean[e0] * rs0;
    const float rs1 = srstd[e1], nmr1 = -smean[e1] * rs1;
    float p0 = 0.f, p1 = 0.f;
#pragma unroll
    for (int msf = 0; msf < 2; ++msf) {
      const float4 gv = *(const float4*)(g2 + featBase + msf * 16 + q * 4);
      const float4 bev = *(const float4*)(be2 + featBase + msf * 16 + q * 4);
      const float4 wv = *(const float4*)(w3 + featBase + msf * 16 + q * 4);
#pragma unroll
      for (int r = 0; r < 4; ++r) {
        const float gr = COMP(gv, r), ber = COMP(bev, r), wr = COMP(wv, r);
        float v0 = fmaxf(fmaf(fmaf(acc2[msf][0][r], rs0, nmr0), gr, ber), 0.f);
        float v1 = fmaxf(fmaf(fmaf(acc2[msf][1][r], rs1, nmr1), gr, ber), 0.f);
        p0 = fmaf(v0, wr, p0);
        p1 = fmaf(v1, wr, p1);
      }
    }
    p0 += __shfl_xor(p0, 16, 64); p0 += __shfl_xor(p0, 32, 64);
    p1 += __shfl_xor(p1, 16, 64); p1 += __shfl_xor(p1, 32, 64);
    if (q == 0) {
      ssum[wf * 64 + e0] = p0;   // ssum dead after b6 reduce
      ssum[wf * 64 + e1] = p1;
    }
  }
  LGKMBAR();  // b7
  if (t < 64) {
    int e = ebase + t;
    if (e < E) {
      float sres = b3[0];
#pragma unroll
      for (int w = 0; w < 8; ++w) sres += ssum[w * 64 + t];
      out[e] = 1.f / (1.f + __expf(-sres));
    }
  }
}

extern "C" void kernel_launch(void* const* d_in, const int* in_sizes, int n_in,
                              void* d_out, int out_size, void* d_ws, size_t ws_size,
                              hipStream_t stream) {
  const float* h = (const float*)d_in[0];
  const int* src = (const int*)d_in[1];
  const int* dst = (const int*)d_in[2];
  const float* W1 = (const float*)d_in[3];
  const float* b1 = (const float*)d_in[4];
  const float* g1 = (const float*)d_in[5];
  const float* be1 = (const float*)d_in[6];
  const float* W2 = (const float*)d_in[7];
  const float* b2 = (const float*)d_in[8];
  const float* g2 = (const float*)d_in[9];
  const float* be2 = (const float*)d_in[10];
  const float* W3 = (const float*)d_in[11];
  const float* b3 = (const float*)d_in[12];
  float* out = (float*)d_out;
  const int E = in_sizes[1];
  const int nrows = in_sizes[0] / 128;
  f16_t* wks = (f16_t*)d_ws;  // 98304 f16 = 196608 bytes

  wconv<<<256, 256, 0, stream>>>(W1, W2, wks);
  (void)hipFuncSetAttribute((const void*)fused_mlp,
                            hipFuncAttributeMaxDynamicSharedMemorySize, LDS_BYTES);
  const int tiles = (E + 63) / 64;
  fused_mlp<<<tiles, 1024, LDS_BYTES, stream>>>(h, src, dst, wks, b1, g1, be1,
                                                b2, g2, be2, W3, b3, out, E, nrows);
}